// Round 14
// baseline (1076.270 us; speedup 1.0000x reference)
//
#include <hip/hip_runtime.h>
#include <hip/hip_bf16.h>
#include <hip/hip_fp16.h>

typedef __attribute__((ext_vector_type(4))) int i32x4;
typedef __attribute__((ext_vector_type(8))) unsigned short u16x8;
typedef __attribute__((ext_vector_type(8))) char c8;
typedef __attribute__((ext_vector_type(4))) char c4;
typedef unsigned int u32;
typedef unsigned short u16;

// ---------- helpers ----------
__device__ __forceinline__ float h2f(u16 u) { return __half2float(__ushort_as_half(u)); }
__device__ __forceinline__ u16  f2h(float f){ return __half_as_ushort(__float2half_rn(f)); }

// ---------- 1. per-token RMS-norm + absmax int8 quant of x ----------
__global__ __launch_bounds__(256) void quant_x_kernel(const float* __restrict__ x,
    char* __restrict__ qx, float* __restrict__ invs) {
  const int D = 2048;
  int row = blockIdx.x, tid = threadIdx.x;
  const float* xr = x + (size_t)row * D;
  float4 a = ((const float4*)xr)[tid * 2], b = ((const float4*)xr)[tid * 2 + 1];
  float v[8] = {a.x, a.y, a.z, a.w, b.x, b.y, b.z, b.w};
  double ss = 0; float mx = 0.0f;
#pragma unroll
  for (int i = 0; i < 8; i++) { ss += (double)v[i] * v[i]; mx = fmaxf(mx, fabsf(v[i])); }
  __shared__ double sd[256]; __shared__ float sf[256];
  sd[tid] = ss; sf[tid] = mx; __syncthreads();
  for (int o = 128; o > 0; o >>= 1) {
    if (tid < o) { sd[tid] += sd[tid + o]; sf[tid] = fmaxf(sf[tid], sf[tid + o]); }
    __syncthreads();
  }
  __shared__ float bn, bs;
  if (tid == 0) {
    float n = fmaxf((float)sqrt(sd[0]), 1e-12f);
    float amax = sf[0] * (sqrtf((float)D) / n);
    float cl = fmaxf(amax, 1e-5f);
    bn = n; bs = 127.0f / cl;
    invs[row] = cl / 127.0f;
  }
  __syncthreads();
  float n = bn, s = bs, sq = sqrtf((float)D);
  c8 q;
#pragma unroll
  for (int i = 0; i < 8; i++) {
    float xn = (v[i] / n) * sq;
    float r = rintf(xn * s);
    r = fminf(fmaxf(r, -128.0f), 127.0f);
    q[i] = (char)(int)r;
  }
  *(c8*)&qx[(size_t)row * D + tid * 8] = q;
}

// ---------- 2. deterministic sum(|w|) partials ----------
__global__ __launch_bounds__(256) void absum_partial(const float* __restrict__ w,
    double* __restrict__ part, int n4) {
  int tid = threadIdx.x;
  double s = 0;
  for (int i = blockIdx.x * 256 + tid; i < n4; i += gridDim.x * 256) {
    float4 v = ((const float4*)w)[i];
    s += (double)fabsf(v.x) + (double)fabsf(v.y) + (double)fabsf(v.z) + (double)fabsf(v.w);
  }
  __shared__ double sd[256];
  sd[tid] = s; __syncthreads();
  for (int o = 128; o > 0; o >>= 1) { if (tid < o) sd[tid] += sd[tid + o]; __syncthreads(); }
  if (tid == 0) part[blockIdx.x] = sd[0];
}

__global__ __launch_bounds__(256) void wscale_final(const double* __restrict__ part,
    float* __restrict__ wsc) {
  int tid = threadIdx.x;
  __shared__ double sd[256];
  sd[tid] = part[tid] + part[tid + 256]; __syncthreads();
  for (int o = 128; o > 0; o >>= 1) { if (tid < o) sd[tid] += sd[tid + o]; __syncthreads(); }
  double s1 = sd[0]; __syncthreads();
  sd[tid] = part[512 + tid] + part[768 + tid]; __syncthreads();
  for (int o = 128; o > 0; o >>= 1) { if (tid < o) sd[tid] += sd[tid + o]; __syncthreads(); }
  if (tid == 0) {
    float m1 = (float)(s1 / 16777216.0);
    float m2 = (float)(sd[0] / 16777216.0);
    float d1 = fmaxf(m1, 1e-5f), d2 = fmaxf(m2, 1e-5f);
    wsc[0] = 1.0f / d1; wsc[1] = d1; wsc[2] = 1.0f / d2; wsc[3] = d2;
  }
}

// ---------- 3. ternary weight quant (stored as i8 {-1,0,1}) ----------
__global__ __launch_bounds__(256) void quant_w_kernel(const float* __restrict__ w,
    char* __restrict__ q, const float* __restrict__ wsc, int widx, int n4) {
  float s = wsc[widx];
  for (int i = blockIdx.x * 256 + threadIdx.x; i < n4; i += gridDim.x * 256) {
    float4 v = ((const float4*)w)[i];
    c4 o;
    o[0] = (char)(int)(fminf(fmaxf(rintf(v.x * s), -1.0f), 1.0f));
    o[1] = (char)(int)(fminf(fmaxf(rintf(v.y * s), -1.0f), 1.0f));
    o[2] = (char)(int)(fminf(fmaxf(rintf(v.z * s), -1.0f), 1.0f));
    o[3] = (char)(int)(fminf(fmaxf(rintf(v.w * s), -1.0f), 1.0f));
    ((c4*)q)[i] = o;
  }
}

// ---------- 4. 128x128 i8 GEMM, DIRECT-FROM-L2 operands: no LDS, no barriers ----------
// A[M][K] x B[N][K], i8, i32 accum (exact). Wave grid 2x2, per-wave 64x64, BK=64.
// Per wave per K-tile: 8 x global_load_dwordx4 (each = 16 rows x 64B contiguous ->
// 16 fully-utilized 64B lines, L2/L3-resident operands) + 16 MFMA. No __shared__,
// no sync; compiler-managed vmcnt. 4 waves/block, <=128 VGPR -> 4 blocks/CU: TLP
// covers L2 latency; matrix pipe ~2x oversubscribed -> saturated.
// EPI==0: dequant + exact GELU -> f16 store.  EPI==1: dequant -> f32 store.
template <int EPI>
__global__ __launch_bounds__(256, 4) void gemm_dr(const char* __restrict__ A,
    const char* __restrict__ B, int N, int K, size_t ldA, size_t ldB, int gridN,
    const float* __restrict__ rowscale, const float* __restrict__ wsc,
    int widx, void* __restrict__ outp) {
  const int tid = threadIdx.x;
  const int lane = tid & 63, w = tid >> 6;
  const int wm = w >> 1, wn = w & 1;               // 2x2 wave grid
  const int llo = lane & 15, lhi = lane >> 4;

  // T1: bijective XCD swizzle (gridDim.x % 8 == 0)
  const int nwg = gridDim.x, cpx = nwg >> 3;
  const int swz = (blockIdx.x & 7) * cpx + (blockIdx.x >> 3);
  const int bm = swz / gridN, bn = swz % gridN;

  const int NT = K >> 6;

  // per-fragment global row pointers (16B-aligned; +t*64 walks K)
  const char* Ap[4];
  const char* Bp[4];
#pragma unroll
  for (int f = 0; f < 4; f++) {
    Ap[f] = A + (size_t)(bm * 128 + wm * 64 + f * 16 + llo) * ldA + lhi * 16;
    Bp[f] = B + (size_t)(bn * 128 + wn * 64 + f * 16 + llo) * ldB + lhi * 16;
  }

  i32x4 acc[4][4];
#pragma unroll
  for (int m = 0; m < 4; m++)
#pragma unroll
    for (int n = 0; n < 4; n++) acc[m][n] = (i32x4){0, 0, 0, 0};

  for (int t = 0; t < NT; t++) {
    const size_t ko = (size_t)t * 64;
    i32x4 a[4], b[4];
#pragma unroll
    for (int f = 0; f < 4; f++) a[f] = *(const i32x4*)(Ap[f] + ko);
#pragma unroll
    for (int f = 0; f < 4; f++) b[f] = *(const i32x4*)(Bp[f] + ko);
#pragma unroll
    for (int m = 0; m < 4; m++)
#pragma unroll
      for (int n = 0; n < 4; n++)
        acc[m][n] = __builtin_amdgcn_mfma_i32_16x16x64_i8(a[m], b[n], acc[m][n], 0, 0, 0);
  }

  // ---- epilogue (i32 -> f32 exact, |acc| << 2^24)
  float wdeq = wsc[widx];
#pragma unroll
  for (int mf = 0; mf < 4; mf++) {
#pragma unroll
    for (int reg = 0; reg < 4; reg++) {
      int r = bm * 128 + wm * 64 + mf * 16 + lhi * 4 + reg;
      float deq = rowscale[r] * wdeq;
#pragma unroll
      for (int nf = 0; nf < 4; nf++) {
        int c = bn * 128 + wn * 64 + nf * 16 + llo;
        float val = (float)acc[mf][nf][reg] * deq;
        if (EPI == 0) {
          float g = 0.5f * val * (1.0f + erff(val * 0.70710678118654752440f));
          ((u16*)outp)[(size_t)r * N + c] = f2h(g);
        } else {
          ((float*)outp)[(size_t)r * N + c] = val;
        }
      }
    }
  }
}

// ---------- 5. per-row norm + quant of h: f16 in, i8 out IN-PLACE (first half of row) ----------
__global__ __launch_bounds__(256) void quant_h_kernel(u16* __restrict__ h, float* __restrict__ invs) {
  const int D = 8192;
  int row = blockIdx.x, tid = threadIdx.x;
  u16* hr = h + (size_t)row * D;
  float v[32];
#pragma unroll
  for (int j = 0; j < 4; j++) {
    u16x8 u = *(const u16x8*)&hr[j * 2048 + tid * 8];
#pragma unroll
    for (int e = 0; e < 8; e++) v[j * 8 + e] = h2f(u[e]);
  }
  double ss = 0; float mx = 0.0f;
#pragma unroll
  for (int i = 0; i < 32; i++) { ss += (double)v[i] * v[i]; mx = fmaxf(mx, fabsf(v[i])); }
  __shared__ double sd[256]; __shared__ float sf[256];
  sd[tid] = ss; sf[tid] = mx; __syncthreads();
  for (int o = 128; o > 0; o >>= 1) {
    if (tid < o) { sd[tid] += sd[tid + o]; sf[tid] = fmaxf(sf[tid], sf[tid + o]); }
    __syncthreads();
  }
  __shared__ float bn, bs;
  if (tid == 0) {
    float n = fmaxf((float)sqrt(sd[0]), 1e-12f);
    float amax = sf[0] * (sqrtf((float)D) / n);
    float cl = fmaxf(amax, 1e-5f);
    bn = n; bs = 127.0f / cl;
    invs[row] = cl / 127.0f;
  }
  __syncthreads();
  float n = bn, s = bs, sq = sqrtf((float)D);
  char* hq = (char*)hr;                     // i8 lands in the first 8192 B of this row
#pragma unroll
  for (int j = 0; j < 4; j++) {
    c8 q;
#pragma unroll
    for (int e = 0; e < 8; e++) {
      float xn = (v[j * 8 + e] / n) * sq;
      float r = rintf(xn * s);
      r = fminf(fmaxf(r, -128.0f), 127.0f);
      q[e] = (char)(int)r;
    }
    *(c8*)&hq[j * 2048 + tid * 8] = q;
  }
}

// ---------- launch ----------
extern "C" void kernel_launch(void* const* d_in, const int* in_sizes, int n_in,
                              void* d_out, int out_size, void* d_ws, size_t ws_size,
                              hipStream_t stream) {
  const float* x  = (const float*)d_in[0];   // [4,2048,2048] f32
  const float* w1 = (const float*)d_in[1];   // [8192,2048]   f32
  const float* w2 = (const float*)d_in[2];   // [2048,8192]   f32

  char* ws = (char*)d_ws;
  char*   qx     = (char*)(ws + 0);            // 8192x2048 i8   (16.8 MB)
  char*   w1q    = (char*)(ws + 16777216);     // 8192x2048 i8   (16.8 MB)
  char*   w2q    = (char*)(ws + 33554432);     // 2048x8192 i8   (16.8 MB)
  u16*    h      = (u16*)(ws + 50331648);      // 8192x8192 f16; i8 in-place after quant (128 MB)
  float*  invs_x = (float*)(ws + 184549376);   // 8192 f32
  float*  invs_h = (float*)(ws + 184582144);   // 8192 f32
  double* part   = (double*)(ws + 184614912);  // 1024 f64
  float*  wsc    = (float*)(ws + 184623104);   // 4 f32: {1/d1, d1, 1/d2, d2}

  quant_x_kernel<<<8192, 256, 0, stream>>>(x, qx, invs_x);
  absum_partial<<<512, 256, 0, stream>>>(w1, part, 4194304);
  absum_partial<<<512, 256, 0, stream>>>(w2, part + 512, 4194304);
  wscale_final<<<1, 256, 0, stream>>>(part, wsc);
  quant_w_kernel<<<2048, 256, 0, stream>>>(w1, w1q, wsc, 0, 4194304);
  quant_w_kernel<<<2048, 256, 0, stream>>>(w2, w2q, wsc, 2, 4194304);
  gemm_dr<0><<<4096, 256, 0, stream>>>(qx, w1q, 8192, 2048, 2048, 2048, 64,
                                       invs_x, wsc, 1, (void*)h);
  quant_h_kernel<<<8192, 256, 0, stream>>>(h, invs_h);
  gemm_dr<1><<<1024, 256, 0, stream>>>((const char*)h, w2q, 2048, 8192, 16384, 8192, 16,
                                       invs_h, wsc, 3, d_out);
}

// Round 15
// 427.613 us; speedup vs baseline: 2.5169x; 2.5169x over previous
//
#include <hip/hip_runtime.h>
#include <hip/hip_bf16.h>
#include <hip/hip_fp16.h>

typedef __attribute__((ext_vector_type(4))) int i32x4;
typedef __attribute__((ext_vector_type(8))) unsigned short u16x8;
typedef __attribute__((ext_vector_type(8))) char c8;
typedef __attribute__((ext_vector_type(4))) char c4;
typedef unsigned int u32;
typedef unsigned short u16;

#define SCH0() __builtin_amdgcn_sched_barrier(0)

// ---------- helpers ----------
__device__ __forceinline__ void gload_lds16(const void* g, void* l) {
  __builtin_amdgcn_global_load_lds((const u32 __attribute__((address_space(1)))*)g,
                                   (u32 __attribute__((address_space(3)))*)l, 16, 0, 0);
}
__device__ __forceinline__ float h2f(u16 u) { return __half2float(__ushort_as_half(u)); }
__device__ __forceinline__ u16  f2h(float f){ return __half_as_ushort(__float2half_rn(f)); }

// ---------- 1. FUSED prep: quant_x (blocks 0..8191) + absum w1 (8192..8703) + absum w2 (8704..9215) ----------
__global__ __launch_bounds__(256) void prep_kernel(const float* __restrict__ x,
    char* __restrict__ qx, float* __restrict__ invs,
    const float* __restrict__ w1, const float* __restrict__ w2,
    double* __restrict__ part) {
  const int tid = threadIdx.x;
  __shared__ double sd[256];
  __shared__ float sf[256];
  if (blockIdx.x < 8192) {
    // ---- quant_x body (identical arithmetic to r10) ----
    const int D = 2048;
    int row = blockIdx.x;
    const float* xr = x + (size_t)row * D;
    float4 a = ((const float4*)xr)[tid * 2], b = ((const float4*)xr)[tid * 2 + 1];
    float v[8] = {a.x, a.y, a.z, a.w, b.x, b.y, b.z, b.w};
    double ss = 0; float mx = 0.0f;
#pragma unroll
    for (int i = 0; i < 8; i++) { ss += (double)v[i] * v[i]; mx = fmaxf(mx, fabsf(v[i])); }
    sd[tid] = ss; sf[tid] = mx; __syncthreads();
    for (int o = 128; o > 0; o >>= 1) {
      if (tid < o) { sd[tid] += sd[tid + o]; sf[tid] = fmaxf(sf[tid], sf[tid + o]); }
      __syncthreads();
    }
    __shared__ float bn, bs;
    if (tid == 0) {
      float n = fmaxf((float)sqrt(sd[0]), 1e-12f);
      float amax = sf[0] * (sqrtf((float)D) / n);
      float cl = fmaxf(amax, 1e-5f);
      bn = n; bs = 127.0f / cl;
      invs[row] = cl / 127.0f;
    }
    __syncthreads();
    float n = bn, s = bs, sq = sqrtf((float)D);
    c8 q;
#pragma unroll
    for (int i = 0; i < 8; i++) {
      float xn = (v[i] / n) * sq;
      float r = rintf(xn * s);
      r = fminf(fmaxf(r, -128.0f), 127.0f);
      q[i] = (char)(int)r;
    }
    *(c8*)&qx[(size_t)row * D + tid * 8] = q;
  } else {
    // ---- absum body (identical loop structure/order to r10: 512 virt blocks, stride 512*256) ----
    const int n4 = 4194304;
    const bool isw2 = blockIdx.x >= 8704;
    const float* w = isw2 ? w2 : w1;
    const int vb = blockIdx.x - (isw2 ? 8704 : 8192);
    double s = 0;
    for (int i = vb * 256 + tid; i < n4; i += 512 * 256) {
      float4 v = ((const float4*)w)[i];
      s += (double)fabsf(v.x) + (double)fabsf(v.y) + (double)fabsf(v.z) + (double)fabsf(v.w);
    }
    sd[tid] = s; __syncthreads();
    for (int o = 128; o > 0; o >>= 1) { if (tid < o) sd[tid] += sd[tid + o]; __syncthreads(); }
    if (tid == 0) part[(isw2 ? 512 : 0) + vb] = sd[0];
  }
}

__global__ __launch_bounds__(256) void wscale_final(const double* __restrict__ part,
    float* __restrict__ wsc) {
  int tid = threadIdx.x;
  __shared__ double sd[256];
  sd[tid] = part[tid] + part[tid + 256]; __syncthreads();
  for (int o = 128; o > 0; o >>= 1) { if (tid < o) sd[tid] += sd[tid + o]; __syncthreads(); }
  double s1 = sd[0]; __syncthreads();
  sd[tid] = part[512 + tid] + part[768 + tid]; __syncthreads();
  for (int o = 128; o > 0; o >>= 1) { if (tid < o) sd[tid] += sd[tid + o]; __syncthreads(); }
  if (tid == 0) {
    float m1 = (float)(s1 / 16777216.0);
    float m2 = (float)(sd[0] / 16777216.0);
    float d1 = fmaxf(m1, 1e-5f), d2 = fmaxf(m2, 1e-5f);
    wsc[0] = 1.0f / d1; wsc[1] = d1; wsc[2] = 1.0f / d2; wsc[3] = d2;
  }
}

// ---------- 2. FUSED ternary weight quant: blocks 0..2047 -> w1, 2048..4095 -> w2 ----------
__global__ __launch_bounds__(256) void quant_w_kernel(const float* __restrict__ w1,
    char* __restrict__ q1, const float* __restrict__ w2, char* __restrict__ q2,
    const float* __restrict__ wsc) {
  const int n4 = 4194304;
  const bool isw2 = blockIdx.x >= 2048;
  const float* w = isw2 ? w2 : w1;
  char* q = isw2 ? q2 : q1;
  float s = isw2 ? wsc[2] : wsc[0];
  const int vb = blockIdx.x - (isw2 ? 2048 : 0);
  for (int i = vb * 256 + threadIdx.x; i < n4; i += 2048 * 256) {
    float4 v = ((const float4*)w)[i];
    c4 o;
    o[0] = (char)(int)(fminf(fmaxf(rintf(v.x * s), -1.0f), 1.0f));
    o[1] = (char)(int)(fminf(fmaxf(rintf(v.y * s), -1.0f), 1.0f));
    o[2] = (char)(int)(fminf(fmaxf(rintf(v.z * s), -1.0f), 1.0f));
    o[3] = (char)(int)(fminf(fmaxf(rintf(v.w * s), -1.0f), 1.0f));
    ((c4*)q)[i] = o;
  }
}

// ---------- 3. 256x256 i8 GEMM, 3-buffer rotation, ONE fused barrier per K-tile ----------
// Identical to the passing r10 kernel except the swz->(bm,bn) map: group-of-4-rows
// serpentine so a co-resident XCD window (32 contiguous swz) covers 4 rows x 8 cols
// (~6 MB working set, mostly L2-resident) instead of 1 row x 32 cols (~16.5 MB).
// Requires gridDim.x % (4*gridN) == 0 (1024%128==0, 256%32==0).
// EPI==0: dequant + exact GELU -> f16 store.  EPI==1: dequant -> f32 store.
template <int EPI>
__global__ __launch_bounds__(512, 2) void gemm_i8(const char* __restrict__ A,
    const char* __restrict__ B, int N, int K, size_t ldA, size_t ldB, int gridN,
    const float* __restrict__ rowscale, const float* __restrict__ wsc,
    int widx, void* __restrict__ outp) {
  __shared__ __align__(16) char sm[3][2][16384];   // [buf][mat][2 halves x 128x64B] = 96 KiB
  const int tid = threadIdx.x;
  const int lane = tid & 63, w = tid >> 6;
  const int wm = w >> 2, wn = w & 3;               // 2M x 4N wave grid
  const int llo = lane & 15, lhi = lane >> 4;
  const int koff = ((lhi ^ ((llo >> 1) & 3)) << 4); // read-side swizzled 16B-block offset

  // T1: bijective XCD swizzle + group-4-row serpentine
  const int nwg = gridDim.x, cpx = nwg >> 3;
  const int swz = (blockIdx.x & 7) * cpx + (blockIdx.x >> 3);
  const int band = gridN << 2;                     // 4 rows per band
  const int g = swz / band, idx = swz % band;
  const int bm = (g << 2) + (idx & 3), bn = idx >> 2;

  const int NT = K >> 6;
  const size_t Abase = (size_t)(bm * 256) * ldA;
  const size_t Bbase = (size_t)(bn * 256) * ldB;

  // staging: thread covers one 16B block (row = tid>>2, kb = tid&3), inverse-swizzled source
  const int rs = tid >> 2;
  const int kbs = (((tid & 3) ^ ((tid >> 3) & 3)) << 4);

  auto stage = [&](int mat, int buf, int hf, int kt) {
    const char* G = (mat == 0) ? A : B;
    size_t ld = (mat == 0) ? ldA : ldB;
    size_t base = (mat == 0) ? Abase : Bbase;
    gload_lds16(G + base + (size_t)(hf * 128 + rs) * ld + (size_t)kt * 64 + kbs,
                &sm[buf][mat][hf * 8192 + tid * 16]);
  };
  auto stage_tile = [&](int buf, int kt) {       // one whole K-tile = 4 loads/thread
    stage(0, buf, 0, kt); stage(1, buf, 0, kt);
    stage(0, buf, 1, kt); stage(1, buf, 1, kt);
  };

  i32x4 alo[4], ahi[4], blo[2], bhi[2];
  auto readA = [&](int buf, int half, i32x4 (&dst)[4]) {
    int rbase = wm * 128 + half * 64 + llo;
#pragma unroll
    for (int f = 0; f < 4; f++)
      dst[f] = *(const i32x4*)&sm[buf][0][(rbase + f * 16) * 64 + koff];
  };
  auto readB = [&](int buf, int half, i32x4 (&dst)[2]) {
    int rbase = wn * 64 + half * 32 + llo;
#pragma unroll
    for (int f = 0; f < 2; f++)
      dst[f] = *(const i32x4*)&sm[buf][1][(rbase + f * 16) * 64 + koff];
  };

  i32x4 acc[8][4];
#pragma unroll
  for (int m = 0; m < 8; m++)
#pragma unroll
    for (int n = 0; n < 4; n++) acc[m][n] = (i32x4){0, 0, 0, 0};

  auto mmaq = [&](i32x4 (&av)[4], i32x4 (&bv)[2], int mh, int nh) {
    __builtin_amdgcn_s_setprio(1);
#pragma unroll
    for (int m = 0; m < 4; m++)
#pragma unroll
      for (int n = 0; n < 2; n++)
        acc[mh * 4 + m][nh * 2 + n] =
            __builtin_amdgcn_mfma_i32_16x16x64_i8(av[m], bv[n],
                                                  acc[mh * 4 + m][nh * 2 + n], 0, 0, 0);
    __builtin_amdgcn_s_setprio(0);
  };

  // prologue: tile0 -> buf0 (4 loads), fence, tile1 -> buf1 (4); retire tile0 whole.
  stage_tile(0, 0);
  asm volatile("s_nop 0" ::: "memory");            // batch boundary fence
  stage_tile(1, 1);
  asm volatile("s_waitcnt vmcnt(4)\n\ts_barrier" ::: "memory");   // tile0 resident; tile1 in flight
  readA(0, 0, alo); readB(0, 0, blo);              // first-half operands of tile 0

  int bR = 0, bN = 1, bS = 2;                       // read / next / stage-target buffers
  for (int t = 0; t < NT; t++) {
    if (t + 2 < NT) stage_tile(bS, t + 2);         // issued at tile top (max latency hiding)
    SCH0();
    readB(bR, 1, bhi);                             // 2 reads under Q0
    SCH0();
    mmaq(alo, blo, 0, 0);                          // Q0 (lo,lo)
    SCH0();
    readA(bR, 1, ahi);                             // 4 reads under Q1
    SCH0();
    mmaq(alo, bhi, 0, 1);                          // Q1 (lo,hi)
    mmaq(ahi, blo, 1, 0);                          // Q2 (hi,lo)
    SCH0();
    if (t + 1 < NT) {
      // ONE barrier per tile: retire stage(t+1) whole (vmcnt), drain this tile's
      // ds_reads (lgkm; WAR for next tile's stage into buf bR), then sync.
      if (t + 2 < NT) asm volatile("s_waitcnt vmcnt(4) lgkmcnt(0)\n\ts_barrier" ::: "memory");
      else            asm volatile("s_waitcnt vmcnt(0) lgkmcnt(0)\n\ts_barrier" ::: "memory");
      readA(bN, 0, alo); readB(bN, 0, blo);        // preload t+1 first halves under Q3
      SCH0();
    }
    mmaq(ahi, bhi, 1, 1);                          // Q3 (hi,hi) — disjoint from preloads
    int tmp = bR; bR = bN; bN = bS; bS = tmp;      // rotate buffers
  }

  // ---- epilogue (i32 -> f32 exact, |acc| << 2^24)
  float wdeq = wsc[widx];
#pragma unroll
  for (int mf = 0; mf < 8; mf++) {
#pragma unroll
    for (int reg = 0; reg < 4; reg++) {
      int r = bm * 256 + wm * 128 + mf * 16 + lhi * 4 + reg;
      float deq = rowscale[r] * wdeq;
#pragma unroll
      for (int nf = 0; nf < 4; nf++) {
        int c = bn * 256 + wn * 64 + nf * 16 + llo;
        float val = (float)acc[mf][nf][reg] * deq;
        if (EPI == 0) {
          float g = 0.5f * val * (1.0f + erff(val * 0.70710678118654752440f));
          ((u16*)outp)[(size_t)r * N + c] = f2h(g);
        } else {
          ((float*)outp)[(size_t)r * N + c] = val;
        }
      }
    }
  }
}

// ---------- 4. per-row norm + quant of h: f16 in, i8 out IN-PLACE (first half of row) ----------
__global__ __launch_bounds__(256) void quant_h_kernel(u16* __restrict__ h, float* __restrict__ invs) {
  const int D = 8192;
  int row = blockIdx.x, tid = threadIdx.x;
  u16* hr = h + (size_t)row * D;
  float v[32];
#pragma unroll
  for (int j = 0; j < 4; j++) {
    u16x8 u = *(const u16x8*)&hr[j * 2048 + tid * 8];
#pragma unroll
    for (int e = 0; e < 8; e++) v[j * 8 + e] = h2f(u[e]);
  }
  double ss = 0; float mx = 0.0f;
#pragma unroll
  for (int i = 0; i < 32; i++) { ss += (double)v[i] * v[i]; mx = fmaxf(mx, fabsf(v[i])); }
  __shared__ double sd[256]; __shared__ float sf[256];
  sd[tid] = ss; sf[tid] = mx; __syncthreads();
  for (int o = 128; o > 0; o >>= 1) {
    if (tid < o) { sd[tid] += sd[tid + o]; sf[tid] = fmaxf(sf[tid], sf[tid + o]); }
    __syncthreads();
  }
  __shared__ float bn, bs;
  if (tid == 0) {
    float n = fmaxf((float)sqrt(sd[0]), 1e-12f);
    float amax = sf[0] * (sqrtf((float)D) / n);
    float cl = fmaxf(amax, 1e-5f);
    bn = n; bs = 127.0f / cl;
    invs[row] = cl / 127.0f;
  }
  __syncthreads();
  float n = bn, s = bs, sq = sqrtf((float)D);
  char* hq = (char*)hr;                     // i8 lands in the first 8192 B of this row
#pragma unroll
  for (int j = 0; j < 4; j++) {
    c8 q;
#pragma unroll
    for (int e = 0; e < 8; e++) {
      float xn = (v[j * 8 + e] / n) * sq;
      float r = rintf(xn * s);
      r = fminf(fmaxf(r, -128.0f), 127.0f);
      q[e] = (char)(int)r;
    }
    *(c8*)&hq[j * 2048 + tid * 8] = q;
  }
}

// ---------- launch ----------
extern "C" void kernel_launch(void* const* d_in, const int* in_sizes, int n_in,
                              void* d_out, int out_size, void* d_ws, size_t ws_size,
                              hipStream_t stream) {
  const float* x  = (const float*)d_in[0];   // [4,2048,2048] f32
  const float* w1 = (const float*)d_in[1];   // [8192,2048]   f32
  const float* w2 = (const float*)d_in[2];   // [2048,8192]   f32

  char* ws = (char*)d_ws;
  char*   qx     = (char*)(ws + 0);            // 8192x2048 i8   (16.8 MB)
  char*   w1q    = (char*)(ws + 16777216);     // 8192x2048 i8   (16.8 MB)
  char*   w2q    = (char*)(ws + 33554432);     // 2048x8192 i8   (16.8 MB)
  u16*    h      = (u16*)(ws + 50331648);      // 8192x8192 f16; i8 in-place after quant (128 MB)
  float*  invs_x = (float*)(ws + 184549376);   // 8192 f32
  float*  invs_h = (float*)(ws + 184582144);   // 8192 f32
  double* part   = (double*)(ws + 184614912);  // 1024 f64
  float*  wsc    = (float*)(ws + 184623104);   // 4 f32: {1/d1, d1, 1/d2, d2}

  prep_kernel<<<9216, 256, 0, stream>>>(x, qx, invs_x, w1, w2, part);
  wscale_final<<<1, 256, 0, stream>>>(part, wsc);
  quant_w_kernel<<<4096, 256, 0, stream>>>(w1, w1q, w2, w2q, wsc);
  gemm_i8<0><<<1024, 512, 0, stream>>>(qx, w1q, 8192, 2048, 2048, 2048, 32,
                                       invs_x, wsc, 1, (void*)h);
  quant_h_kernel<<<8192, 256, 0, stream>>>(h, invs_h);
  gemm_i8<1><<<256, 512, 0, stream>>>((const char*)h, w2q, 2048, 8192, 16384, 8192, 8,
                                      invs_h, wsc, 3, d_out);
}

// Round 17
// 421.652 us; speedup vs baseline: 2.5525x; 1.0141x over previous
//
#include <hip/hip_runtime.h>
#include <hip/hip_bf16.h>
#include <hip/hip_fp16.h>

typedef __attribute__((ext_vector_type(4))) int i32x4;
typedef __attribute__((ext_vector_type(8))) unsigned short u16x8;
typedef __attribute__((ext_vector_type(8))) char c8;
typedef __attribute__((ext_vector_type(4))) char c4;
typedef unsigned int u32;
typedef unsigned short u16;

#define SCH0() __builtin_amdgcn_sched_barrier(0)

// ---------- helpers ----------
__device__ __forceinline__ void gload_lds16(const void* g, void* l) {
  __builtin_amdgcn_global_load_lds((const u32 __attribute__((address_space(1)))*)g,
                                   (u32 __attribute__((address_space(3)))*)l, 16, 0, 0);
}
__device__ __forceinline__ float h2f(u16 u) { return __half2float(__ushort_as_half(u)); }
__device__ __forceinline__ u16  f2h(float f){ return __half_as_ushort(__float2half_rn(f)); }

// ---------- 1. FUSED prep: quant_x (blocks 0..8191) + absum w1 (8192..8703) + absum w2 (8704..9215) ----------
__global__ __launch_bounds__(256) void prep_kernel(const float* __restrict__ x,
    char* __restrict__ qx, float* __restrict__ invs,
    const float* __restrict__ w1, const float* __restrict__ w2,
    double* __restrict__ part) {
  const int tid = threadIdx.x;
  __shared__ double sd[256];
  __shared__ float sf[256];
  if (blockIdx.x < 8192) {
    const int D = 2048;
    int row = blockIdx.x;
    const float* xr = x + (size_t)row * D;
    float4 a = ((const float4*)xr)[tid * 2], b = ((const float4*)xr)[tid * 2 + 1];
    float v[8] = {a.x, a.y, a.z, a.w, b.x, b.y, b.z, b.w};
    double ss = 0; float mx = 0.0f;
#pragma unroll
    for (int i = 0; i < 8; i++) { ss += (double)v[i] * v[i]; mx = fmaxf(mx, fabsf(v[i])); }
    sd[tid] = ss; sf[tid] = mx; __syncthreads();
    for (int o = 128; o > 0; o >>= 1) {
      if (tid < o) { sd[tid] += sd[tid + o]; sf[tid] = fmaxf(sf[tid], sf[tid + o]); }
      __syncthreads();
    }
    __shared__ float bn, bs;
    if (tid == 0) {
      float n = fmaxf((float)sqrt(sd[0]), 1e-12f);
      float amax = sf[0] * (sqrtf((float)D) / n);
      float cl = fmaxf(amax, 1e-5f);
      bn = n; bs = 127.0f / cl;
      invs[row] = cl / 127.0f;
    }
    __syncthreads();
    float n = bn, s = bs, sq = sqrtf((float)D);
    c8 q;
#pragma unroll
    for (int i = 0; i < 8; i++) {
      float xn = (v[i] / n) * sq;
      float r = rintf(xn * s);
      r = fminf(fmaxf(r, -128.0f), 127.0f);
      q[i] = (char)(int)r;
    }
    *(c8*)&qx[(size_t)row * D + tid * 8] = q;
  } else {
    const int n4 = 4194304;
    const bool isw2 = blockIdx.x >= 8704;
    const float* w = isw2 ? w2 : w1;
    const int vb = blockIdx.x - (isw2 ? 8704 : 8192);
    double s = 0;
    for (int i = vb * 256 + tid; i < n4; i += 512 * 256) {
      float4 v = ((const float4*)w)[i];
      s += (double)fabsf(v.x) + (double)fabsf(v.y) + (double)fabsf(v.z) + (double)fabsf(v.w);
    }
    sd[tid] = s; __syncthreads();
    for (int o = 128; o > 0; o >>= 1) { if (tid < o) sd[tid] += sd[tid + o]; __syncthreads(); }
    if (tid == 0) part[(isw2 ? 512 : 0) + vb] = sd[0];
  }
}

__global__ __launch_bounds__(256) void wscale_final(const double* __restrict__ part,
    float* __restrict__ wsc) {
  int tid = threadIdx.x;
  __shared__ double sd[256];
  sd[tid] = part[tid] + part[tid + 256]; __syncthreads();
  for (int o = 128; o > 0; o >>= 1) { if (tid < o) sd[tid] += sd[tid + o]; __syncthreads(); }
  double s1 = sd[0]; __syncthreads();
  sd[tid] = part[512 + tid] + part[768 + tid]; __syncthreads();
  for (int o = 128; o > 0; o >>= 1) { if (tid < o) sd[tid] += sd[tid + o]; __syncthreads(); }
  if (tid == 0) {
    float m1 = (float)(s1 / 16777216.0);
    float m2 = (float)(sd[0] / 16777216.0);
    float d1 = fmaxf(m1, 1e-5f), d2 = fmaxf(m2, 1e-5f);
    wsc[0] = 1.0f / d1; wsc[1] = d1; wsc[2] = 1.0f / d2; wsc[3] = d2;
  }
}

// ---------- 2. FUSED ternary weight quant ----------
__global__ __launch_bounds__(256) void quant_w_kernel(const float* __restrict__ w1,
    char* __restrict__ q1, const float* __restrict__ w2, char* __restrict__ q2,
    const float* __restrict__ wsc) {
  const int n4 = 4194304;
  const bool isw2 = blockIdx.x >= 2048;
  const float* w = isw2 ? w2 : w1;
  char* q = isw2 ? q2 : q1;
  float s = isw2 ? wsc[2] : wsc[0];
  const int vb = blockIdx.x - (isw2 ? 2048 : 0);
  for (int i = vb * 256 + threadIdx.x; i < n4; i += 2048 * 256) {
    float4 v = ((const float4*)w)[i];
    c4 o;
    o[0] = (char)(int)(fminf(fmaxf(rintf(v.x * s), -1.0f), 1.0f));
    o[1] = (char)(int)(fminf(fmaxf(rintf(v.y * s), -1.0f), 1.0f));
    o[2] = (char)(int)(fminf(fmaxf(rintf(v.z * s), -1.0f), 1.0f));
    o[3] = (char)(int)(fminf(fmaxf(rintf(v.w * s), -1.0f), 1.0f));
    ((c4*)q)[i] = o;
  }
}

// ---------- 3. 256x256 i8 GEMM: r15 kernel with manual unroll-3 so all LDS buffer
// indices are COMPILE-TIME constants into the typed __shared__ array (guaranteed
// ds_read/gload_lds addrspace; loop-invariant base VGPRs + immediate offsets).
// Sync ledger, batch order, serpentine raster: byte-for-byte r15 (passing).
#define READ_A3(BUF, HALF, DST)                                            \
  { _Pragma("unroll") for (int f_ = 0; f_ < 4; f_++)                       \
      DST[f_] = *(const i32x4*)&sm[BUF][0][(wm * 128 + (HALF) * 64 + llo + f_ * 16) * 64 + koff]; }
#define READ_B3(BUF, HALF, DST)                                            \
  { _Pragma("unroll") for (int f_ = 0; f_ < 2; f_++)                       \
      DST[f_] = *(const i32x4*)&sm[BUF][1][(wn * 64 + (HALF) * 32 + llo + f_ * 16) * 64 + koff]; }
#define MMAQ(AV, BV, MH, NH)                                               \
  { __builtin_amdgcn_s_setprio(1);                                         \
    _Pragma("unroll") for (int m_ = 0; m_ < 4; m_++)                       \
      _Pragma("unroll") for (int n_ = 0; n_ < 2; n_++)                     \
        acc[(MH) * 4 + m_][(NH) * 2 + n_] =                                \
            __builtin_amdgcn_mfma_i32_16x16x64_i8(AV[m_], BV[n_],          \
                acc[(MH) * 4 + m_][(NH) * 2 + n_], 0, 0, 0);               \
    __builtin_amdgcn_s_setprio(0); }
#define STAGE3(BUF, KT)                                                    \
  { size_t ko_ = (size_t)(KT) * 64;                                        \
    gload_lds16(gA0 + ko_, &sm[BUF][0][tid * 16]);                         \
    gload_lds16(gB0 + ko_, &sm[BUF][1][tid * 16]);                         \
    gload_lds16(gA1 + ko_, &sm[BUF][0][8192 + tid * 16]);                  \
    gload_lds16(gB1 + ko_, &sm[BUF][1][8192 + tid * 16]); }
#define TILE_M(BR, BN, BS, KT)                                             \
  { STAGE3(BS, (KT) + 2);                                                  \
    SCH0();                                                                \
    READ_B3(BR, 1, bhi); SCH0();                                           \
    MMAQ(alo, blo, 0, 0); SCH0();                                          \
    READ_A3(BR, 1, ahi); SCH0();                                           \
    MMAQ(alo, bhi, 0, 1);                                                  \
    MMAQ(ahi, blo, 1, 0); SCH0();                                          \
    asm volatile("s_waitcnt vmcnt(4) lgkmcnt(0)\n\ts_barrier" ::: "memory"); \
    READ_A3(BN, 0, alo); READ_B3(BN, 0, blo); SCH0();                      \
    MMAQ(ahi, bhi, 1, 1); }

// EPI==0: dequant + exact GELU -> f16 store.  EPI==1: dequant -> f32 store.
template <int EPI>
__global__ __launch_bounds__(512, 2) void gemm_i8(const char* __restrict__ A,
    const char* __restrict__ B, int N, int K, size_t ldA, size_t ldB, int gridN,
    const float* __restrict__ rowscale, const float* __restrict__ wsc,
    int widx, void* __restrict__ outp) {
  __shared__ __align__(16) char sm[3][2][16384];   // [buf][mat][2 halves x 128x64B] = 96 KiB
  const int tid = threadIdx.x;
  const int lane = tid & 63, w = tid >> 6;
  const int wm = w >> 2, wn = w & 3;               // 2M x 4N wave grid
  const int llo = lane & 15, lhi = lane >> 4;
  const int koff = ((lhi ^ ((llo >> 1) & 3)) << 4); // read-side swizzled 16B-block offset

  // T1: bijective XCD swizzle + group-4-row serpentine (r15)
  const int nwg = gridDim.x, cpx = nwg >> 3;
  const int swz = (blockIdx.x & 7) * cpx + (blockIdx.x >> 3);
  const int band = gridN << 2;
  const int g = swz / band, idx = swz % band;
  const int bm = (g << 2) + (idx & 3), bn = idx >> 2;

  const int NT = K >> 6;                           // 32 or 128; NT % 3 == 2
  const int NITER = (NT - 2) / 3;

  // staging source pointers (r15 address expression, hoisted)
  const int rs = tid >> 2;
  const int kbs = (((tid & 3) ^ ((tid >> 3) & 3)) << 4);
  const char* gA0 = A + (size_t)(bm * 256 + rs) * ldA + kbs;
  const char* gA1 = gA0 + (size_t)128 * ldA;
  const char* gB0 = B + (size_t)(bn * 256 + rs) * ldB + kbs;
  const char* gB1 = gB0 + (size_t)128 * ldB;

  i32x4 alo[4], ahi[4], blo[2], bhi[2];
  i32x4 acc[8][4];
#pragma unroll
  for (int m = 0; m < 8; m++)
#pragma unroll
    for (int n = 0; n < 4; n++) acc[m][n] = (i32x4){0, 0, 0, 0};

  // prologue: t0 -> buf0, fence, t1 -> buf1; retire t0 whole (r15 ledger)
  STAGE3(0, 0);
  asm volatile("s_nop 0" ::: "memory");            // batch boundary fence
  STAGE3(1, 1);
  asm volatile("s_waitcnt vmcnt(4)\n\ts_barrier" ::: "memory");   // tile0 resident
  READ_A3(0, 0, alo); READ_B3(0, 0, blo);

  for (int it = 0, t = 0; it < NITER; ++it, t += 3) {
    TILE_M(0, 1, 2, t);
    TILE_M(1, 2, 0, t + 1);
    TILE_M(2, 0, 1, t + 2);
  }
  // tail t = NT-2 (buf0): no stage, vmcnt(0)
  {
    SCH0();
    READ_B3(0, 1, bhi); SCH0();
    MMAQ(alo, blo, 0, 0); SCH0();
    READ_A3(0, 1, ahi); SCH0();
    MMAQ(alo, bhi, 0, 1);
    MMAQ(ahi, blo, 1, 0); SCH0();
    asm volatile("s_waitcnt vmcnt(0) lgkmcnt(0)\n\ts_barrier" ::: "memory");
    READ_A3(1, 0, alo); READ_B3(1, 0, blo); SCH0();
    MMAQ(ahi, bhi, 1, 1);
  }
  // tail t = NT-1 (buf1): no stage, no sync
  {
    READ_B3(1, 1, bhi);
    MMAQ(alo, blo, 0, 0);
    READ_A3(1, 1, ahi);
    MMAQ(alo, bhi, 0, 1);
    MMAQ(ahi, blo, 1, 0);
    MMAQ(ahi, bhi, 1, 1);
  }

  // ---- epilogue (i32 -> f32 exact, |acc| << 2^24)
  float wdeq = wsc[widx];
#pragma unroll
  for (int mf = 0; mf < 8; mf++) {
#pragma unroll
    for (int reg = 0; reg < 4; reg++) {
      int r = bm * 256 + wm * 128 + mf * 16 + lhi * 4 + reg;
      float deq = rowscale[r] * wdeq;
#pragma unroll
      for (int nf = 0; nf < 4; nf++) {
        int c = bn * 256 + wn * 64 + nf * 16 + llo;
        float val = (float)acc[mf][nf][reg] * deq;
        if (EPI == 0) {
          float gg = 0.5f * val * (1.0f + erff(val * 0.70710678118654752440f));
          ((u16*)outp)[(size_t)r * N + c] = f2h(gg);
        } else {
          ((float*)outp)[(size_t)r * N + c] = val;
        }
      }
    }
  }
}

// ---------- 4. per-row norm + quant of h: f16 in, i8 out IN-PLACE ----------
__global__ __launch_bounds__(256) void quant_h_kernel(u16* __restrict__ h, float* __restrict__ invs) {
  const int D = 8192;
  int row = blockIdx.x, tid = threadIdx.x;
  u16* hr = h + (size_t)row * D;
  float v[32];
#pragma unroll
  for (int j = 0; j < 4; j++) {
    u16x8 u = *(const u16x8*)&hr[j * 2048 + tid * 8];
#pragma unroll
    for (int e = 0; e < 8; e++) v[j * 8 + e] = h2f(u[e]);
  }
  double ss = 0; float mx = 0.0f;
#pragma unroll
  for (int i = 0; i < 32; i++) { ss += (double)v[i] * v[i]; mx = fmaxf(mx, fabsf(v[i])); }
  __shared__ double sd[256]; __shared__ float sf[256];
  sd[tid] = ss; sf[tid] = mx; __syncthreads();
  for (int o = 128; o > 0; o >>= 1) {
    if (tid < o) { sd[tid] += sd[tid + o]; sf[tid] = fmaxf(sf[tid], sf[tid + o]); }
    __syncthreads();
  }
  __shared__ float bn, bs;
  if (tid == 0) {
    float n = fmaxf((float)sqrt(sd[0]), 1e-12f);
    float amax = sf[0] * (sqrtf((float)D) / n);
    float cl = fmaxf(amax, 1e-5f);
    bn = n; bs = 127.0f / cl;
    invs[row] = cl / 127.0f;
  }
  __syncthreads();
  float n = bn, s = bs, sq = sqrtf((float)D);
  char* hq = (char*)hr;
#pragma unroll
  for (int j = 0; j < 4; j++) {
    c8 q;
#pragma unroll
    for (int e = 0; e < 8; e++) {
      float xn = (v[j * 8 + e] / n) * sq;
      float r = rintf(xn * s);
      r = fminf(fmaxf(r, -128.0f), 127.0f);
      q[e] = (char)(int)r;
    }
    *(c8*)&hq[j * 2048 + tid * 8] = q;
  }
}

// ---------- launch ----------
extern "C" void kernel_launch(void* const* d_in, const int* in_sizes, int n_in,
                              void* d_out, int out_size, void* d_ws, size_t ws_size,
                              hipStream_t stream) {
  const float* x  = (const float*)d_in[0];   // [4,2048,2048] f32
  const float* w1 = (const float*)d_in[1];   // [8192,2048]   f32
  const float* w2 = (const float*)d_in[2];   // [2048,8192]   f32

  char* ws = (char*)d_ws;
  char*   qx     = (char*)(ws + 0);            // 8192x2048 i8
  char*   w1q    = (char*)(ws + 16777216);     // 8192x2048 i8
  char*   w2q    = (char*)(ws + 33554432);     // 2048x8192 i8
  u16*    h      = (u16*)(ws + 50331648);      // 8192x8192 f16; i8 in-place after quant
  float*  invs_x = (float*)(ws + 184549376);
  float*  invs_h = (float*)(ws + 184582144);
  double* part   = (double*)(ws + 184614912);
  float*  wsc    = (float*)(ws + 184623104);

  prep_kernel<<<9216, 256, 0, stream>>>(x, qx, invs_x, w1, w2, part);
  wscale_final<<<1, 256, 0, stream>>>(part, wsc);
  quant_w_kernel<<<4096, 256, 0, stream>>>(w1, w1q, w2, w2q, wsc);
  gemm_i8<0><<<1024, 512, 0, stream>>>(qx, w1q, 8192, 2048, 2048, 2048, 32,
                                       invs_x, wsc, 1, (void*)h);
  quant_h_kernel<<<8192, 256, 0, stream>>>(h, invs_h);
  gemm_i8<1><<<256, 512, 0, stream>>>((const char*)h, w2q, 2048, 8192, 16384, 8192, 8,
                                      invs_h, wsc, 3, d_out);
}